// Round 5
// baseline (132.776 us; speedup 1.0000x reference)
//
#include <hip/hip_runtime.h>
#include <math.h>

// Problem constants
constexpr int L    = 4096;   // seq len
constexpr int D    = 1024;   // d_model
constexpr int N    = 16;     // hiddens per channel
constexpr int CPB  = 16;     // channels per block = one full 64B line per row
constexpr int NCG  = D / CPB;     // 64 channel groups
constexpr int NSEG = 4;           // L segments (carry resolved across dispatches)
constexpr int LSEG = L / NSEG;    // 1024 rows per block
constexpr int NB   = NCG * NSEG;  // 256 blocks for kernel B
constexpr int NT   = 1024;        // 16 waves
constexpr int NCH  = 32;          // chunks per block
constexpr int T    = LSEG / NCH;  // 32 rows per chunk
constexpr int NST  = CPB * N;     // 256 state-cols per block
constexpr int SSTR = NST + 1;     // 257: odd float2 stride -> <=4-way banks

typedef float v2 __attribute__((ext_vector_type(2)));

__device__ __forceinline__ float softplus_f(float v) {
    return fmaxf(v, 0.0f) + log1pf(expf(-fabsf(v)));
}

// Fast Lambda = exp(dt*(ar + i*ai)) via HW transcendentals.
__device__ __forceinline__ void lam_fast(float ar, float ai, float dt,
                                         float& lr, float& li) {
    float e = __expf(ar * dt);
    float s, c;
    __sincosf(ai * dt, &s, &c);
    lr = e * c;
    li = e * s;
}

__device__ __forceinline__ v2 vfma(v2 a, v2 b, v2 c) {
    return __builtin_elementwise_fma(a, b, c);
}

// ============================================================================
// Two-dispatch full-line design (R2/R4 counters: CPB=4 partial-line I/O costs
// FETCH 2x = 32MB, WRITE 4x = 65MB with no L2 merging; R3 proved grid.sync +
// threadfence poisons everything). Block (seg, cgi) owns rows [seg*1024,+1024)
// x channels [cgi*16,+16): every global access is a full private 64B line.
// Kernel boundary = free device-wide ordering (no fences needed).
//   A: per-segment state summary -> sb (ws).  B: carry from sb, full compute.
// ============================================================================

// Per-thread Lambda for 8 states (n = h*8..h*8+7), packed into v2[4].
__device__ __forceinline__ void lam_pack(const float* A_re, const float* A_im,
                                         int d, int h, float dt,
                                         v2 LR[4], v2 LI[4]) {
    const int base = d * N + h * 8;
    float4 a0 = *(const float4*)(A_re + base);
    float4 a1 = *(const float4*)(A_re + base + 4);
    float4 m0 = *(const float4*)(A_im + base);
    float4 m1 = *(const float4*)(A_im + base + 4);
    const float ar[8] = {a0.x, a0.y, a0.z, a0.w, a1.x, a1.y, a1.z, a1.w};
    const float ai[8] = {m0.x, m0.y, m0.z, m0.w, m1.x, m1.y, m1.z, m1.w};
    #pragma unroll
    for (int p = 0; p < 4; ++p) {
        float lr0, li0, lr1, li1;
        lam_fast(ar[2 * p], ai[2 * p], dt, lr0, li0);
        lam_fast(ar[2 * p + 1], ai[2 * p + 1], dt, lr1, li1);
        LR[p] = (v2){lr0, lr1};
        LI[p] = (v2){li0, li1};
    }
}

// Lambda^32 for flat state s (s = n*16 + dd).
__device__ __forceinline__ void lam32_state(const float* Delta,
                                            const float* A_re, const float* A_im,
                                            int c0, int s,
                                            float& l32r, float& l32i) {
    const int sdd = s & 15, sn = s >> 4;
    const int d2 = c0 + sdd;
    const float dt2 = softplus_f(Delta[d2]);
    lam_fast(A_re[d2 * N + sn], A_im[d2 * N + sn], dt2, l32r, l32i);
    #pragma unroll
    for (int k = 0; k < 5; ++k) {     // Lam^32 (T = 32)
        float nr = l32r * l32r - l32i * l32i;
        l32i = 2.0f * l32r * l32i;
        l32r = nr;
    }
}

// ---- Kernel A: segment summaries (segs 0..2 only; seg 3's is unused) ----
// Thread t: h=t&1, dd=(t>>1)&15, ct=t>>5. x read directly from global:
// per wave-load, lanes cover 2 full 64B lines (+h-duplicate broadcast).
__global__ __launch_bounds__(NT) void k_sum(
    const float* __restrict__ x, const float* __restrict__ Delta,
    const float* __restrict__ A_re, const float* __restrict__ A_im,
    float2* __restrict__ sb)
{
    __shared__ float2 sums[NCH * SSTR];   // 65.8 KB chunk summaries
    __shared__ float2 tot[4 * NST];       // 8 KB quarter totals

    const int blk = blockIdx.x;           // 0..191
    const int cgi = blk & (NCG - 1);
    const int seg = blk >> 6;
    const int l0  = seg * LSEG;
    const int c0  = cgi * CPB;
    const int t   = threadIdx.x;
    const int h   = t & 1;
    const int dd  = (t >> 1) & 15;
    const int ct  = t >> 5;
    const int d   = c0 + dd;
    const float dt = softplus_f(Delta[d]);

    v2 LR[4], LI[4];
    lam_pack(A_re, A_im, d, h, dt, LR, LI);

    // local scan of chunk ct straight from global
    v2 GR[4] = {(v2)0, (v2)0, (v2)0, (v2)0};
    v2 GI[4] = {(v2)0, (v2)0, (v2)0, (v2)0};
    const float* xp = x + (size_t)(l0 + ct * T) * D + d;
    #pragma unroll 4
    for (int i = 0; i < T; ++i) {
        float xv = xp[(size_t)i * D];
        v2 XV = (v2){xv, xv};
        #pragma unroll
        for (int p = 0; p < 4; ++p) {
            v2 t2 = vfma(-LI[p], GI[p], XV);
            v2 nr = vfma(LR[p], GR[p], t2);
            GI[p] = vfma(LR[p], GI[p], LI[p] * GR[p]);
            GR[p] = nr;
        }
    }
    #pragma unroll
    for (int p = 0; p < 4; ++p) {
        const int s0 = (h * 8 + 2 * p) * CPB + dd;    // state = n*16 + dd
        sums[ct * SSTR + s0]       = make_float2(GR[p].x, GI[p].x);
        sums[ct * SSTR + s0 + CPB] = make_float2(GR[p].y, GI[p].y);
    }

    const int lane = t & 63, w = t >> 6, SL = w & 3, WG = w >> 2;
    const int s = SL * 64 + lane;
    float l32r, l32i;
    lam32_state(Delta, A_re, A_im, c0, s, l32r, l32i);
    __syncthreads();   // chunk summaries ready

    // fold 8 chunks (no prefix needed in A)
    {
        float cr = 0.0f, ci = 0.0f;
        #pragma unroll
        for (int k = 0; k < 8; ++k) {
            float2 sv = sums[(WG * 8 + k) * SSTR + s];
            float nr = fmaf(l32r, cr, fmaf(-l32i, ci, sv.x));
            ci = fmaf(l32r, ci, fmaf(l32i, cr, sv.y));
            cr = nr;
        }
        tot[WG * NST + s] = make_float2(cr, ci);
    }
    __syncthreads();   // quarter totals ready

    if (w < 4) {       // waves 0..3 cover all 256 states: fold 4 quarters
        float rr = l32r, ri = l32i;
        #pragma unroll
        for (int k = 0; k < 3; ++k) {     // Lam^256 = (Lam^32)^8
            float nr = rr * rr - ri * ri;
            ri = 2.0f * rr * ri;
            rr = nr;
        }
        float cr = 0.0f, ci = 0.0f;
        #pragma unroll
        for (int u = 0; u < 4; ++u) {
            float2 sv = tot[u * NST + s];
            float nr = fmaf(rr, cr, fmaf(-ri, ci, sv.x));
            ci = fmaf(rr, ci, fmaf(ri, cr, sv.y));
            cr = nr;
        }
        sb[((size_t)seg * NCG + cgi) * NST + s] = make_float2(cr, ci);
    }
}

// ---- Kernel B: full compute with carry from sb (R3 body, fences removed) ----
__global__ __launch_bounds__(NT, 4) void k_main(
    const float* __restrict__ x,
    const float* __restrict__ Delta,
    const float* __restrict__ A_re, const float* __restrict__ A_im,
    const float* __restrict__ B_re, const float* __restrict__ B_im,
    const float* __restrict__ C_re, const float* __restrict__ C_im,
    const float* __restrict__ Dp,
    float* __restrict__ out,
    const float2* __restrict__ sb)
{
    __shared__ float  xs[LSEG * CPB];     // 64 KB  [row][ch]
    __shared__ float2 sums[NCH * SSTR];   // 65.8 KB [chunk][state(+pad)]
    __shared__ float2 tot[4 * NST];       // 8 KB   [wave-quarter][state]

    const int blk = blockIdx.x;
    const int cgi = blk & (NCG - 1);
    const int seg = blk >> 6;
    const int l0  = seg * LSEG;
    const int c0  = cgi * CPB;
    const int t   = threadIdx.x;

    const int lane = t & 63, w = t >> 6, SL = w & 3, WG = w >> 2;
    const int s = SL * 64 + lane;

    // preceding-segment summaries issued first: latency hides under staging
    float2 sseg[NSEG - 1];
    if (seg > 0) {
        for (int j = 0; j < seg; ++j)
            sseg[j] = sb[((size_t)j * NCG + cgi) * NST + s];
    }

    // ---- phase 0: stage x slab, full-line loads (4 lanes q cover 64B) ----
    {
        const int q = t & 3, r = t >> 2;
        float4 v[4];
        #pragma unroll
        for (int k = 0; k < 4; ++k)
            v[k] = *(const float4*)(x + (size_t)(l0 + r + 256 * k) * D + c0 + q * 4);
        #pragma unroll
        for (int k = 0; k < 4; ++k)
            *(float4*)&xs[(r + 256 * k) * CPB + q * 4] = v[k];
    }

    const int h  = t & 1;
    const int dd = (t >> 1) & 15;
    const int ct = t >> 5;
    const int d  = c0 + dd;
    const float dt = softplus_f(Delta[d]);

    v2 LR[4], LI[4];
    lam_pack(A_re, A_im, d, h, dt, LR, LI);
    __syncthreads();   // (1) xs ready

    // ---- phase 1: local scan of chunk ct, zero init ----
    v2 GR[4] = {(v2)0, (v2)0, (v2)0, (v2)0};
    v2 GI[4] = {(v2)0, (v2)0, (v2)0, (v2)0};
    #pragma unroll 4
    for (int i = 0; i < T; ++i) {
        float xv = xs[(ct * T + i) * CPB + dd];
        v2 XV = (v2){xv, xv};
        #pragma unroll
        for (int p = 0; p < 4; ++p) {
            v2 t2 = vfma(-LI[p], GI[p], XV);
            v2 nr = vfma(LR[p], GR[p], t2);
            GI[p] = vfma(LR[p], GI[p], LI[p] * GR[p]);
            GR[p] = nr;
        }
    }
    #pragma unroll
    for (int p = 0; p < 4; ++p) {
        const int s0 = (h * 8 + 2 * p) * CPB + dd;
        sums[ct * SSTR + s0]       = make_float2(GR[p].x, GI[p].x);
        sums[ct * SSTR + s0 + CPB] = make_float2(GR[p].y, GI[p].y);
    }

    float l32r, l32i;
    lam32_state(Delta, A_re, A_im, c0, s, l32r, l32i);
    __syncthreads();   // (2) chunk summaries ready

    // pass 1: wave scans its 8 chunks (exclusive); quarter total -> tot[WG]
    {
        float cr = 0.0f, ci = 0.0f;
        #pragma unroll
        for (int k = 0; k < 8; ++k) {
            const int idx = (WG * 8 + k) * SSTR + s;
            float2 sv = sums[idx];
            sums[idx] = make_float2(cr, ci);     // local exclusive prefix P
            float nr = fmaf(l32r, cr, fmaf(-l32i, ci, sv.x));
            ci = fmaf(l32r, ci, fmaf(l32i, cr, sv.y));
            cr = nr;
        }
        tot[WG * NST + s] = make_float2(cr, ci);
    }

    // ---- phase 3 params issued here: latency hides under pass 2 ----
    float4 pb0, pb1, pe0, pe1, pf0, pf1, pg0, pg1;
    {
        const int base = d * N + h * 8;
        pb0 = *(const float4*)(B_re + base);
        pb1 = *(const float4*)(B_re + base + 4);
        pe0 = *(const float4*)(B_im + base);
        pe1 = *(const float4*)(B_im + base + 4);
        pf0 = *(const float4*)(C_re + base);
        pf1 = *(const float4*)(C_re + base + 4);
        pg0 = *(const float4*)(C_im + base);
        pg1 = *(const float4*)(C_im + base + 4);
    }
    const float dpv = Dp[d];

    __syncthreads();   // (3) quarter totals ready

    // pass 2: waves 0..3 exclusive-scan the 4 quarter-totals (ratio Lam^256)
    if (w < 4) {
        float rr = l32r, ri = l32i;
        #pragma unroll
        for (int k = 0; k < 3; ++k) {     // Lam^256
            float nr = rr * rr - ri * ri;
            ri = 2.0f * rr * ri;
            rr = nr;
        }
        float cr = 0.0f, ci = 0.0f;
        #pragma unroll
        for (int u = 0; u < 4; ++u) {
            const int idx = u * NST + s;
            float2 sv = tot[idx];
            tot[idx] = make_float2(cr, ci);   // exclusive quarter carry G
            float nr = fmaf(rr, cr, fmaf(-ri, ci, sv.x));
            ci = fmaf(rr, ci, fmaf(ri, cr, sv.y));
            cr = nr;
        }
    }
    __syncthreads();   // (4) quarter carries G ready

    // ---- carry: C = sum_j Lam^(1024*(seg-1-j)) * S_j  (<=3 terms) ----
    float Cr = 0.0f, Ci = 0.0f;
    if (seg > 0) {
        float g1r = l32r, g1i = l32i;
        #pragma unroll
        for (int k = 0; k < 5; ++k) {     // Lam^1024 = (Lam^32)^32
            float nr = g1r * g1r - g1i * g1i;
            g1i = 2.0f * g1r * g1i;
            g1r = nr;
        }
        for (int j = 0; j < seg; ++j) {
            float nr = fmaf(g1r, Cr, fmaf(-g1i, Ci, sseg[j].x));
            Ci = fmaf(g1r, Ci, fmaf(g1i, Cr, sseg[j].y));
            Cr = nr;
        }
    }

    // pass 3: chunk carries = Lam^(32k) * (Lam^(256*WG)*C + G) + P
    {
        float rr = l32r, ri = l32i;
        #pragma unroll
        for (int k = 0; k < 3; ++k) {     // Lam^256
            float nr = rr * rr - ri * ri;
            ri = 2.0f * rr * ri;
            rr = nr;
        }
        float pr = 1.0f, pi = 0.0f;       // Lam^(256*WG), WG wave-uniform
        for (int k = 0; k < WG; ++k) {
            float nr = pr * rr - pi * ri;
            pi = fmaf(pr, ri, pi * rr);
            pr = nr;
        }
        float2 g = tot[WG * NST + s];
        float cr = fmaf(pr, Cr, fmaf(-pi, Ci, g.x));
        float ci = fmaf(pr, Ci, fmaf(pi, Cr, g.y));
        #pragma unroll
        for (int k = 0; k < 8; ++k) {
            const int idx = (WG * 8 + k) * SSTR + s;
            float2 p = sums[idx];
            sums[idx] = make_float2(cr + p.x, ci + p.y);
            float nr = l32r * cr - l32i * ci;
            ci = fmaf(l32r, ci, l32i * cr);
            cr = nr;
        }
    }

    // ---- C' = dt*(C*B), D (packed) ----
    v2 CR[4], CI[4];
    {
        const float br[8] = {pb0.x, pb0.y, pb0.z, pb0.w, pb1.x, pb1.y, pb1.z, pb1.w};
        const float bi[8] = {pe0.x, pe0.y, pe0.z, pe0.w, pe1.x, pe1.y, pe1.z, pe1.w};
        const float cr[8] = {pf0.x, pf0.y, pf0.z, pf0.w, pf1.x, pf1.y, pf1.z, pf1.w};
        const float ci[8] = {pg0.x, pg0.y, pg0.z, pg0.w, pg1.x, pg1.y, pg1.z, pg1.w};
        #pragma unroll
        for (int p = 0; p < 4; ++p) {
            CR[p] = (v2){dt * (cr[2*p] * br[2*p] - ci[2*p] * bi[2*p]),
                         dt * (cr[2*p+1] * br[2*p+1] - ci[2*p+1] * bi[2*p+1])};
            CI[p] = (v2){dt * (cr[2*p] * bi[2*p] + ci[2*p] * br[2*p]),
                         dt * (cr[2*p+1] * bi[2*p+1] + ci[2*p+1] * br[2*p+1])};
        }
    }
    __syncthreads();   // (5) final chunk carries ready

    // ---- phase 3: rescan from carry, contract, transpose, full-line store ----
    #pragma unroll
    for (int p = 0; p < 4; ++p) {
        const int s0 = (h * 8 + 2 * p) * CPB + dd;
        float2 c0v = sums[ct * SSTR + s0];
        float2 c1v = sums[ct * SSTR + s0 + CPB];
        GR[p] = (v2){c0v.x, c1v.x};
        GI[p] = (v2){c0v.y, c1v.y};
    }
    const float dsel0 = h ? 0.0f : dpv;   // fold D-term exactly once (own parity)
    const float dsel1 = h ? dpv  : 0.0f;
    const int r0 = dd & 3;
    const int cb = c0 + (dd >> 2) * 4;    // this lane's 16B segment of the line
    #pragma unroll
    for (int ob = 0; ob < T / 8; ++ob) {
        float P0[4], P1[4];
        #pragma unroll
        for (int ib = 0; ib < 4; ++ib) {
            #pragma unroll
            for (int u = 0; u < 2; ++u) {
                int i = ob * 8 + ib * 2 + u;
                float xv = xs[(ct * T + i) * CPB + dd];
                v2 XV = (v2){xv, xv};
                v2 ACC = (v2)0;
                #pragma unroll
                for (int p = 0; p < 4; ++p) {
                    v2 t2 = vfma(-LI[p], GI[p], XV);
                    v2 nr = vfma(LR[p], GR[p], t2);
                    GI[p] = vfma(LR[p], GI[p], LI[p] * GR[p]);
                    GR[p] = nr;
                    ACC = vfma(CR[p], GR[p], ACC);
                    ACC = vfma(-CI[p], GI[p], ACC);
                }
                float ap = ACC.x + ACC.y;
                ap = fmaf(u == 0 ? dsel0 : dsel1, xv, ap);
                if (u == 0) P0[ib] = ap; else P1[ib] = ap;
            }
        }
        // deferred h-combine: 1 shfl per row-pair
        float Vh[4];
        #pragma unroll
        for (int ib = 0; ib < 4; ++ib) {
            float mine  = h ? P1[ib] : P0[ib];
            float other = h ? P0[ib] : P1[ib];
            Vh[ib] = mine + __shfl_xor(other, 1);
        }
        // 4-lane transpose over r0 = dd&3; the 4 lanes dd>>2 = 0..3 of a wave
        // tile the full 64B output line of row ob*8 + r0*2 + h.
        float f[4];
        f[r0]     = Vh[r0];
        f[r0 ^ 1] = __shfl_xor(Vh[r0 ^ 1], 2);
        f[r0 ^ 2] = __shfl_xor(Vh[r0 ^ 2], 4);
        f[r0 ^ 3] = __shfl_xor(Vh[r0 ^ 3], 6);
        int row = l0 + ct * T + ob * 8 + r0 * 2 + h;
        *(float4*)(out + (size_t)row * D + cb) =
            make_float4(f[0], f[1], f[2], f[3]);
    }
}

extern "C" void kernel_launch(void* const* d_in, const int* in_sizes, int n_in,
                              void* d_out, int out_size, void* d_ws, size_t ws_size,
                              hipStream_t stream) {
    const float* x     = (const float*)d_in[0];
    const float* Delta = (const float*)d_in[1];
    const float* A_re  = (const float*)d_in[2];
    const float* A_im  = (const float*)d_in[3];
    const float* B_re  = (const float*)d_in[4];
    const float* B_im  = (const float*)d_in[5];
    const float* C_re  = (const float*)d_in[6];
    const float* C_im  = (const float*)d_in[7];
    const float* Dp    = (const float*)d_in[8];
    float* out = (float*)d_out;

    // summaries for segs 0..2: 3 * 64 * 256 * 8B = 384 KB. The harness
    // workspace is the 256 MiB poison-filled buffer (fill counters), so the
    // d_ws path is the one that runs; d_out fallback only if ws is absent.
    const size_t need = sizeof(float2) * (size_t)(NSEG - 1) * NCG * NST;
    float2* sb = (d_ws != nullptr && ws_size >= need) ? (float2*)d_ws
                                                      : (float2*)d_out;

    k_sum<<<dim3((NSEG - 1) * NCG), dim3(NT), 0, stream>>>(
        x, Delta, A_re, A_im, sb);
    k_main<<<dim3(NB), dim3(NT), 0, stream>>>(
        x, Delta, A_re, A_im, B_re, B_im, C_re, C_im, Dp, out, sb);
}

// Round 6
// 128.494 us; speedup vs baseline: 1.0333x; 1.0333x over previous
//
#include <hip/hip_runtime.h>
#include <math.h>

// Problem constants
constexpr int L   = 4096;   // seq len
constexpr int D   = 1024;   // d_model
constexpr int N   = 16;     // hiddens per channel
constexpr int CPB = 4;      // channels per block
constexpr int NB  = D / CPB;   // 256 blocks (1 per CU)
constexpr int NCB = 128;    // chunks per block
constexpr int T   = L / NCB;   // 32 steps per chunk
constexpr int NT  = 1024;   // threads per block (16 waves, 4/SIMD)
constexpr int PAD = 65;     // sums chunk stride in float2 (kills the 32-way
                            // bank conflict; residual 4-way is ~free)

typedef float v2 __attribute__((ext_vector_type(2)));

__device__ __forceinline__ float softplus_f(float v) {
    return fmaxf(v, 0.0f) + log1pf(expf(-fabsf(v)));
}

// Fast Lambda = exp(dt*(ar + i*ai)) via HW transcendentals.
__device__ __forceinline__ void lam_fast(float ar, float ai, float dt,
                                         float& lr, float& li) {
    float e = __expf(ar * dt);
    float s, c;
    __sincosf(ai * dt, &s, &c);
    lr = e * c;
    li = e * s;
}

__device__ __forceinline__ v2 vfma(v2 a, v2 b, v2 c) {
    return __builtin_elementwise_fma(a, b, c);
}

// One dispatch, 256 blocks (1/CU). Block owns channels [d0, d0+4) x full L.
// Thread t: h = t&1 (n-half), dd = (t>>1)&3 (channel), ct = t>>3 (chunk).
//
// This is the R1 skeleton (best measured: dur 103.17, kernel ~33us) with two
// scheduling-only deltas:
//  - B/C/Dp param loads issued right after the staging loads (drain under
//    phases 1-2 instead of exposing latency between barriers 3-5)
//  - phase-3 deferred h-combine (1 shfl per row-pair; arithmetic-equivalent,
//    verified in R2 with identical absmax)
//
// Lessons encoded (R2-R5 counters):
//  - WRITE_SIZE ~65-70MB is HARNESS EVICTION BACKLOG (256MB poison fill
//    draining through L2/LLC during our window) - insensitive to store
//    pattern. Full-line-ownership restructures (CPB=16, 2-dispatch,
//    grid.sync) all regressed: 50-57us vs 33us here. Do not chase it.
//  - global_load_lds on scattered 64B lines: -24us regression (R4). Keep
//    register staging.
//  - The 5 __syncthreads and the 256-blocks-share-rows layout are part of
//    why this structure wins (cross-block L2 reuse of x lines).
__global__ __launch_bounds__(NT, 4) void k_fused(
    const float* __restrict__ x,
    const float* __restrict__ Delta,
    const float* __restrict__ A_re, const float* __restrict__ A_im,
    const float* __restrict__ B_re, const float* __restrict__ B_im,
    const float* __restrict__ C_re, const float* __restrict__ C_im,
    const float* __restrict__ Dp,
    float* __restrict__ out)
{
    __shared__ float  xs[T * 512];        // [i][ct][dd]: word i*512+ct*4+dd
    __shared__ float2 sums[NCB * PAD];    // [ct][dd*16+n], padded, 66.5 KB
    __shared__ float2 tot[16 * 64];       // per-wave totals/carries, 8 KB

    const int b  = blockIdx.x;
    const int d0 = (b & 7) * 128 + (b >> 3) * 4;   // XCD-contiguous channels
    const int t  = threadIdx.x;

    // ---- phase 0: stage x[0..L) x [d0, d0+4) into LDS, float4 loads ----
    {
        const int sct = t & 127;          // chunk
        const int si  = t >> 7;           // 0..7: which 4-row group
        float4 v[4];
        #pragma unroll
        for (int k = 0; k < 4; ++k) {
            int l = sct * T + si * 4 + k;
            v[k] = *(const float4*)(x + (size_t)l * D + d0);
        }
        #pragma unroll
        for (int k = 0; k < 4; ++k)
            *(float4*)&xs[(si * 4 + k) * 512 + sct * 4] = v[k];
    }

    const int h  = t & 1;
    const int dd = (t >> 1) & 3;
    const int ct = t >> 3;
    const int d  = d0 + dd;

    // ---- params issued early: queue behind staging, drain under phase 1-2 ----
    float4 pb0, pb1, pe0, pe1, pf0, pf1, pg0, pg1;
    {
        const int base = d * N + h * 8;
        pb0 = *(const float4*)(B_re + base);
        pb1 = *(const float4*)(B_re + base + 4);
        pe0 = *(const float4*)(B_im + base);
        pe1 = *(const float4*)(B_im + base + 4);
        pf0 = *(const float4*)(C_re + base);
        pf1 = *(const float4*)(C_re + base + 4);
        pg0 = *(const float4*)(C_im + base);
        pg1 = *(const float4*)(C_im + base + 4);
    }
    const float dpv = Dp[d];
    const float dt  = softplus_f(Delta[d]);

    // ---- per-thread Lambda for its 8 states (n = h*8..h*8+7), packed ----
    v2 LR[4], LI[4];
    {
        const int base = d * N + h * 8;
        float4 a0 = *(const float4*)(A_re + base);
        float4 a1 = *(const float4*)(A_re + base + 4);
        float4 m0 = *(const float4*)(A_im + base);
        float4 m1 = *(const float4*)(A_im + base + 4);
        const float ar[8] = {a0.x, a0.y, a0.z, a0.w, a1.x, a1.y, a1.z, a1.w};
        const float ai[8] = {m0.x, m0.y, m0.z, m0.w, m1.x, m1.y, m1.z, m1.w};
        #pragma unroll
        for (int p = 0; p < 4; ++p) {
            float lr0, li0, lr1, li1;
            lam_fast(ar[2 * p], ai[2 * p], dt, lr0, li0);
            lam_fast(ar[2 * p + 1], ai[2 * p + 1], dt, lr1, li1);
            LR[p] = (v2){lr0, lr1};
            LI[p] = (v2){li0, li1};
        }
    }
    __syncthreads();   // (1) xs ready

    // ---- phase 1: local scan of chunk ct, zero init ----
    v2 GR[4] = {(v2)0, (v2)0, (v2)0, (v2)0};
    v2 GI[4] = {(v2)0, (v2)0, (v2)0, (v2)0};
    #pragma unroll 4
    for (int i = 0; i < T; ++i) {
        float xv = xs[i * 512 + ct * 4 + dd];
        v2 XV = (v2){xv, xv};
        #pragma unroll
        for (int p = 0; p < 4; ++p) {
            v2 t2 = vfma(-LI[p], GI[p], XV);
            v2 nr = vfma(LR[p], GR[p], t2);
            GI[p] = vfma(LR[p], GI[p], LI[p] * GR[p]);
            GR[p] = nr;
        }
    }
    {
        float2* sp = &sums[ct * PAD + dd * 16 + h * 8];
        #pragma unroll
        for (int p = 0; p < 4; ++p) {
            sp[2 * p]     = make_float2(GR[p].x, GI[p].x);
            sp[2 * p + 1] = make_float2(GR[p].y, GI[p].y);
        }
    }

    // ---- phase 2 roles: lane = (dd2, n2) pair, wave w owns chunks 8w..8w+7 ----
    const int lane = t & 63;
    const int w    = t >> 6;
    float l32r, l32i;           // Lambda^32 for this lane's (dd2, n2)
    {
        const int dd2 = lane >> 4, n2 = lane & 15;
        const int d2  = d0 + dd2;
        const float dt2 = softplus_f(Delta[d2]);
        lam_fast(A_re[d2 * N + n2], A_im[d2 * N + n2], dt2, l32r, l32i);
        #pragma unroll
        for (int k = 0; k < 5; ++k) {     // Lam^32 (T = 32)
            float nr = l32r * l32r - l32i * l32i;
            l32i = 2.0f * l32r * l32i;
            l32r = nr;
        }
    }
    __syncthreads();   // (2) summaries ready

    // pass 1: per-wave exclusive scan of its 8 chunks; total -> tot[w]
    {
        float cr = 0.0f, ci = 0.0f;
        #pragma unroll
        for (int k = 0; k < 8; ++k) {
            const int idx = (w * 8 + k) * PAD + lane;
            float2 sv = sums[idx];
            sums[idx] = make_float2(cr, ci);     // local exclusive prefix P
            float nr = fmaf(l32r, cr, fmaf(-l32i, ci, sv.x));
            ci = fmaf(l32r, ci, fmaf(l32i, cr, sv.y));
            cr = nr;
        }
        tot[w * 64 + lane] = make_float2(cr, ci);   // S_w
    }
    __syncthreads();   // (3) all wave totals visible to wave 0

    // pass 2: wave 0 scans the 16 wave-totals with ratio Lam^256
    if (t < 64) {
        float rr = l32r, ri = l32i;
        #pragma unroll
        for (int k = 0; k < 3; ++k) {     // Lam^256 = (Lam^32)^8
            float nr = rr * rr - ri * ri;
            ri = 2.0f * rr * ri;
            rr = nr;
        }
        float cr = 0.0f, ci = 0.0f;
        #pragma unroll
        for (int u = 0; u < 16; ++u) {
            float2 sv = tot[u * 64 + t];
            tot[u * 64 + t] = make_float2(cr, ci);   // exclusive G_w
            float nr = fmaf(rr, cr, fmaf(-ri, ci, sv.x));
            ci = fmaf(rr, ci, fmaf(ri, cr, sv.y));
            cr = nr;
        }
    }
    __syncthreads();   // (4) wave carries G_w ready

    // pass 3: C_{8w+k} = Lam^(32k) * G_w + P_{w,k}
    {
        float2 g = tot[w * 64 + lane];
        float gr = g.x, gi = g.y;
        #pragma unroll
        for (int k = 0; k < 8; ++k) {
            const int idx = (w * 8 + k) * PAD + lane;
            float2 p = sums[idx];
            sums[idx] = make_float2(gr + p.x, gi + p.y);
            float nr = l32r * gr - l32i * gi;
            gi = fmaf(l32r, gi, l32i * gr);
            gr = nr;
        }
    }

    // ---- C' = dt*(C*B) from pre-loaded regs (pure VALU) ----
    v2 CR[4], CI[4];
    {
        const float br[8] = {pb0.x, pb0.y, pb0.z, pb0.w, pb1.x, pb1.y, pb1.z, pb1.w};
        const float bi[8] = {pe0.x, pe0.y, pe0.z, pe0.w, pe1.x, pe1.y, pe1.z, pe1.w};
        const float cr[8] = {pf0.x, pf0.y, pf0.z, pf0.w, pf1.x, pf1.y, pf1.z, pf1.w};
        const float ci[8] = {pg0.x, pg0.y, pg0.z, pg0.w, pg1.x, pg1.y, pg1.z, pg1.w};
        #pragma unroll
        for (int p = 0; p < 4; ++p) {
            CR[p] = (v2){dt * (cr[2*p] * br[2*p] - ci[2*p] * bi[2*p]),
                         dt * (cr[2*p+1] * br[2*p+1] - ci[2*p+1] * bi[2*p+1])};
            CI[p] = (v2){dt * (cr[2*p] * bi[2*p] + ci[2*p] * br[2*p]),
                         dt * (cr[2*p+1] * bi[2*p+1] + ci[2*p+1] * br[2*p+1])};
        }
    }
    __syncthreads();   // (5) final chunk carries ready

    // ---- phase 3: rescan from carry, contract, transpose-store ----
    {
        const float2* cp = &sums[ct * PAD + dd * 16 + h * 8];
        #pragma unroll
        for (int p = 0; p < 4; ++p) {
            float2 c0 = cp[2 * p], c1 = cp[2 * p + 1];
            GR[p] = (v2){c0.x, c1.x};
            GI[p] = (v2){c0.y, c1.y};
        }
    }
    // D-term folded exactly once (own parity slot only).
    const float dsel0 = h ? 0.0f : dpv;
    const float dsel1 = h ? dpv  : 0.0f;
    #pragma unroll
    for (int ob = 0; ob < T / 8; ++ob) {
        float P0[4], P1[4];
        #pragma unroll
        for (int ib = 0; ib < 4; ++ib) {
            #pragma unroll
            for (int u = 0; u < 2; ++u) {
                int i = ob * 8 + ib * 2 + u;
                float xv = xs[i * 512 + ct * 4 + dd];
                v2 XV = (v2){xv, xv};
                v2 ACC = (v2)0;
                #pragma unroll
                for (int p = 0; p < 4; ++p) {
                    v2 t2 = vfma(-LI[p], GI[p], XV);
                    v2 nr = vfma(LR[p], GR[p], t2);
                    GI[p] = vfma(LR[p], GI[p], LI[p] * GR[p]);
                    GR[p] = nr;
                    ACC = vfma(CR[p], GR[p], ACC);
                    ACC = vfma(-CI[p], GI[p], ACC);
                }
                float ap = ACC.x + ACC.y;
                ap = fmaf(u == 0 ? dsel0 : dsel1, xv, ap);  // my parity only
                if (u == 0) P0[ib] = ap; else P1[ib] = ap;
            }
        }
        // deferred h-combine: full(u=h) = P_me[h] + P_partner[h] (1 shfl/pair)
        float Vh[4];
        #pragma unroll
        for (int ib = 0; ib < 4; ++ib) {
            float mine  = h ? P1[ib] : P0[ib];
            float other = h ? P0[ib] : P1[ib];
            Vh[ib] = mine + __shfl_xor(other, 1);
        }
        // 4-lane transpose over dd (lane bits 1..2): lane (h,dd) assembles the
        // full 4-channel segment of row rr = ob*8 + dd*2 + h.
        float f[4];
        f[dd]     = Vh[dd];
        f[dd ^ 1] = __shfl_xor(Vh[dd ^ 1], 2);
        f[dd ^ 2] = __shfl_xor(Vh[dd ^ 2], 4);
        f[dd ^ 3] = __shfl_xor(Vh[dd ^ 3], 6);
        int row = ct * T + ob * 8 + dd * 2 + h;
        *(float4*)(out + (size_t)row * D + d0) =
            make_float4(f[0], f[1], f[2], f[3]);   // 16 B/lane store
    }
}

extern "C" void kernel_launch(void* const* d_in, const int* in_sizes, int n_in,
                              void* d_out, int out_size, void* d_ws, size_t ws_size,
                              hipStream_t stream) {
    const float* x     = (const float*)d_in[0];
    const float* Delta = (const float*)d_in[1];
    const float* A_re  = (const float*)d_in[2];
    const float* A_im  = (const float*)d_in[3];
    const float* B_re  = (const float*)d_in[4];
    const float* B_im  = (const float*)d_in[5];
    const float* C_re  = (const float*)d_in[6];
    const float* C_im  = (const float*)d_in[7];
    const float* Dp    = (const float*)d_in[8];
    float* out = (float*)d_out;

    k_fused<<<NB, NT, 0, stream>>>(x, Delta, A_re, A_im, B_re, B_im,
                                   C_re, C_im, Dp, out);
}

// Round 7
// 104.437 us; speedup vs baseline: 1.2714x; 1.2304x over previous
//
#include <hip/hip_runtime.h>
#include <math.h>

// ============================================================================
// ANCHOR REVERT — byte-identical compute to the Round-1 kernel that measured
// dur_us = 103.17 (best of 7 benches). Rounds 2-6 (wave-sync restructure,
// CPB=16 full-line, 2-dispatch, global_load_lds, early-params + deferred
// h-combine) ALL measured k_fused/k_main at 50-57us vs this structure's
// inferred ~32-35us. This round is a controlled A/B against the environment:
//   - if dur returns to ~103: the R6 deltas (param hoist / deferred combine)
//     caused the regression -> this kernel is terminal-best.
//   - if dur stays ~128: regression is environmental (fill interleave);
//     all variants are equivalent within that noise.
// Known-insensitive counters (R2/R4/R6): FETCH~32MB WRITE~65MB regardless of
// access pattern = poison-fill eviction backlog, not kernel traffic. Do not
// optimize against them.
// ============================================================================

// Problem constants
constexpr int L   = 4096;   // seq len
constexpr int D   = 1024;   // d_model
constexpr int N   = 16;     // hiddens per channel
constexpr int CPB = 4;      // channels per block
constexpr int NB  = D / CPB;   // 256 blocks (1 per CU)
constexpr int NCB = 128;    // chunks per block
constexpr int T   = L / NCB;   // 32 steps per chunk
constexpr int NT  = 1024;   // threads per block (16 waves, 4/SIMD)
constexpr int PAD = 65;     // sums chunk stride in float2 (64 -> 65 kills the
                            // 32-way bank conflict; residual 4-way is ~free)

typedef float v2 __attribute__((ext_vector_type(2)));

__device__ __forceinline__ float softplus_f(float v) {
    return fmaxf(v, 0.0f) + log1pf(expf(-fabsf(v)));
}

// Fast Lambda = exp(dt*(ar + i*ai)) via HW transcendentals.
__device__ __forceinline__ void lam_fast(float ar, float ai, float dt,
                                         float& lr, float& li) {
    float e = __expf(ar * dt);
    float s, c;
    __sincosf(ai * dt, &s, &c);
    lr = e * c;
    li = e * s;
}

__device__ __forceinline__ v2 vfma(v2 a, v2 b, v2 c) {
    return __builtin_elementwise_fma(a, b, c);
}

// One dispatch, 256 blocks (1/CU). Block owns channels [d0, d0+4) x full L.
// Thread t: h = t&1 (n-half, 8 states), dd = (t>>1)&3 (channel), ct = t>>3
// (chunk of T=32). All cross-thread dataflow is intra-block (LDS + shfl).
//   0) stage x slice via float4 loads (16 B/lane)   -> xs[i][ct][dd], 64 KB
//   1) local scan of chunk ct (packed fp32)         -> sums[ct][dd*16+n]
//   2) 3-pass parallel chunk scan:
//      p1: each wave w scans its 8 chunks (exclusive), totals -> tot[w]
//      p2: wave 0 scans the 16 wave-totals with ratio Lam^256
//      p3: each wave adds Lam^(32k)*G_w to its local prefixes
//   3) rescan from carry, contract C'=dt*C*B, h-shfl reduce, then 4-lane
//      in-register transpose (3 shfl_xor) -> one float4 row-segment store
//      per lane (16 B/lane)
// d0 swizzle: blocks b, b+8, b+16, b+24 (same XCD under round-robin) share
// each 64 B x-line -> reuse served by that XCD's L2.
__global__ __launch_bounds__(NT, 4) void k_fused(
    const float* __restrict__ x,
    const float* __restrict__ Delta,
    const float* __restrict__ A_re, const float* __restrict__ A_im,
    const float* __restrict__ B_re, const float* __restrict__ B_im,
    const float* __restrict__ C_re, const float* __restrict__ C_im,
    const float* __restrict__ Dp,
    float* __restrict__ out)
{
    __shared__ float  xs[T * 512];        // [i][ct][dd]: word i*512+ct*4+dd
    __shared__ float2 sums[NCB * PAD];    // [ct][dd*16+n], padded, 66.5 KB
    __shared__ float2 tot[16 * 64];       // per-wave totals/carries, 8 KB

    const int b  = blockIdx.x;
    const int d0 = (b & 7) * 128 + (b >> 3) * 4;   // XCD-contiguous channels
    const int t  = threadIdx.x;

    // ---- phase 0: stage x[0..L) x [d0, d0+4) into LDS, float4 loads ----
    {
        const int sct = t & 127;          // chunk
        const int si  = t >> 7;           // 0..7: which 4-row group
        float4 v[4];
        #pragma unroll
        for (int k = 0; k < 4; ++k) {
            int l = sct * T + si * 4 + k;
            v[k] = *(const float4*)(x + (size_t)l * D + d0);
        }
        #pragma unroll
        for (int k = 0; k < 4; ++k)
            *(float4*)&xs[(si * 4 + k) * 512 + sct * 4] = v[k];
    }

    const int h  = t & 1;
    const int dd = (t >> 1) & 3;
    const int ct = t >> 3;
    const int d  = d0 + dd;
    const float dt = softplus_f(Delta[d]);

    // ---- per-thread Lambda for its 8 states (n = h*8..h*8+7), packed ----
    v2 LR[4], LI[4];
    {
        const int base = d * N + h * 8;
        float4 a0 = *(const float4*)(A_re + base);
        float4 a1 = *(const float4*)(A_re + base + 4);
        float4 m0 = *(const float4*)(A_im + base);
        float4 m1 = *(const float4*)(A_im + base + 4);
        const float ar[8] = {a0.x, a0.y, a0.z, a0.w, a1.x, a1.y, a1.z, a1.w};
        const float ai[8] = {m0.x, m0.y, m0.z, m0.w, m1.x, m1.y, m1.z, m1.w};
        #pragma unroll
        for (int p = 0; p < 4; ++p) {
            float lr0, li0, lr1, li1;
            lam_fast(ar[2 * p], ai[2 * p], dt, lr0, li0);
            lam_fast(ar[2 * p + 1], ai[2 * p + 1], dt, lr1, li1);
            LR[p] = (v2){lr0, lr1};
            LI[p] = (v2){li0, li1};
        }
    }
    __syncthreads();   // xs ready

    // ---- phase 1: local scan of chunk ct, zero init ----
    v2 GR[4] = {(v2)0, (v2)0, (v2)0, (v2)0};
    v2 GI[4] = {(v2)0, (v2)0, (v2)0, (v2)0};
    #pragma unroll 4
    for (int i = 0; i < T; ++i) {
        float xv = xs[i * 512 + ct * 4 + dd];
        v2 XV = (v2){xv, xv};
        #pragma unroll
        for (int p = 0; p < 4; ++p) {
            v2 t2 = vfma(-LI[p], GI[p], XV);
            v2 nr = vfma(LR[p], GR[p], t2);
            GI[p] = vfma(LR[p], GI[p], LI[p] * GR[p]);
            GR[p] = nr;
        }
    }
    {
        float2* sp = &sums[ct * PAD + dd * 16 + h * 8];
        #pragma unroll
        for (int p = 0; p < 4; ++p) {
            sp[2 * p]     = make_float2(GR[p].x, GI[p].x);
            sp[2 * p + 1] = make_float2(GR[p].y, GI[p].y);
        }
    }

    // ---- phase 2: parallel scan over the 128 chunk summaries ----
    const int lane = t & 63;
    const int w    = t >> 6;
    float l32r, l32i;           // Lambda^32 for this lane's (dd2, n2)
    {
        const int dd2 = lane >> 4, n2 = lane & 15;
        const int d2  = d0 + dd2;
        const float dt2 = softplus_f(Delta[d2]);
        lam_fast(A_re[d2 * N + n2], A_im[d2 * N + n2], dt2, l32r, l32i);
        #pragma unroll
        for (int k = 0; k < 5; ++k) {     // Lam^32 (T = 32)
            float nr = l32r * l32r - l32i * l32i;
            l32i = 2.0f * l32r * l32i;
            l32r = nr;
        }
    }
    __syncthreads();   // summaries ready

    // pass 1: per-wave exclusive scan of its 8 chunks; total -> tot[w]
    {
        float cr = 0.0f, ci = 0.0f;
        #pragma unroll
        for (int k = 0; k < 8; ++k) {
            const int idx = (w * 8 + k) * PAD + lane;
            float2 sv = sums[idx];
            sums[idx] = make_float2(cr, ci);     // local exclusive prefix P
            float nr = fmaf(l32r, cr, fmaf(-l32i, ci, sv.x));
            ci = fmaf(l32r, ci, fmaf(l32i, cr, sv.y));
            cr = nr;
        }
        tot[w * 64 + lane] = make_float2(cr, ci);   // S_w
    }

    // ---- phase 3 params: issue global loads so they fly during pass 2 ----
    float4 b0, b1, e0, e1, f0, f1, g0, g1;
    {
        const int base = d * N + h * 8;
        b0 = *(const float4*)(B_re + base);
        b1 = *(const float4*)(B_re + base + 4);
        e0 = *(const float4*)(B_im + base);
        e1 = *(const float4*)(B_im + base + 4);
        f0 = *(const float4*)(C_re + base);
        f1 = *(const float4*)(C_re + base + 4);
        g0 = *(const float4*)(C_im + base);
        g1 = *(const float4*)(C_im + base + 4);
    }
    const float dpv = Dp[d];

    __syncthreads();   // A: all wave totals visible to wave 0

    // pass 2: wave 0 scans the 16 wave-totals with ratio Lam^256
    if (t < 64) {
        float rr = l32r, ri = l32i;
        #pragma unroll
        for (int k = 0; k < 3; ++k) {     // Lam^256 = (Lam^32)^8
            float nr = rr * rr - ri * ri;
            ri = 2.0f * rr * ri;
            rr = nr;
        }
        float cr = 0.0f, ci = 0.0f;
        #pragma unroll
        for (int u = 0; u < 16; ++u) {
            float2 sv = tot[u * 64 + t];
            tot[u * 64 + t] = make_float2(cr, ci);   // exclusive G_w
            float nr = fmaf(rr, cr, fmaf(-ri, ci, sv.x));
            ci = fmaf(rr, ci, fmaf(ri, cr, sv.y));
            cr = nr;
        }
    }

    __syncthreads();   // B: wave carries G_w ready

    // pass 3: C_{8w+k} = Lam^(32k) * G_w + P_{w,k}
    {
        float2 g = tot[w * 64 + lane];
        float gr = g.x, gi = g.y;
        #pragma unroll
        for (int k = 0; k < 8; ++k) {
            const int idx = (w * 8 + k) * PAD + lane;
            float2 p = sums[idx];
            sums[idx] = make_float2(gr + p.x, gi + p.y);
            float nr = l32r * gr - l32i * gi;
            gi = fmaf(l32r, gi, l32i * gr);
            gr = nr;
        }
    }

    // ---- phase 3 params: C' = dt*(C*B), D (packed) ----
    v2 CR[4], CI[4];
    {
        const float br[8] = {b0.x, b0.y, b0.z, b0.w, b1.x, b1.y, b1.z, b1.w};
        const float bi[8] = {e0.x, e0.y, e0.z, e0.w, e1.x, e1.y, e1.z, e1.w};
        const float cr[8] = {f0.x, f0.y, f0.z, f0.w, f1.x, f1.y, f1.z, f1.w};
        const float ci[8] = {g0.x, g0.y, g0.z, g0.w, g1.x, g1.y, g1.z, g1.w};
        #pragma unroll
        for (int p = 0; p < 4; ++p) {
            CR[p] = (v2){dt * (cr[2*p] * br[2*p] - ci[2*p] * bi[2*p]),
                         dt * (cr[2*p+1] * br[2*p+1] - ci[2*p+1] * bi[2*p+1])};
            CI[p] = (v2){dt * (cr[2*p] * bi[2*p] + ci[2*p] * br[2*p]),
                         dt * (cr[2*p+1] * bi[2*p+1] + ci[2*p+1] * br[2*p+1])};
        }
    }

    __syncthreads();   // carries ready

    // ---- phase 3: rescan from carry, contract, transpose-store ----
    {
        const float2* cp = &sums[ct * PAD + dd * 16 + h * 8];
        #pragma unroll
        for (int p = 0; p < 4; ++p) {
            float2 c0 = cp[2 * p], c1 = cp[2 * p + 1];
            GR[p] = (v2){c0.x, c1.x};
            GI[p] = (v2){c0.y, c1.y};
        }
    }
    #pragma unroll
    for (int ob = 0; ob < T / 8; ++ob) {
        float Vh[4];
        #pragma unroll
        for (int ib = 0; ib < 4; ++ib) {
            #pragma unroll
            for (int u = 0; u < 2; ++u) {
                int i = ob * 8 + ib * 2 + u;
                float xv = xs[i * 512 + ct * 4 + dd];
                v2 XV = (v2){xv, xv};
                v2 ACC = (v2)0;
                #pragma unroll
                for (int p = 0; p < 4; ++p) {
                    v2 t2 = vfma(-LI[p], GI[p], XV);
                    v2 nr = vfma(LR[p], GR[p], t2);
                    GI[p] = vfma(LR[p], GI[p], LI[p] * GR[p]);
                    GR[p] = nr;
                    ACC = vfma(CR[p], GR[p], ACC);
                    ACC = vfma(-CI[p], GI[p], ACC);
                }
                float acc = ACC.x + ACC.y;
                acc += __shfl_xor(acc, 1);       // combine the two n-halves
                acc = fmaf(dpv, xv, acc);        // finished value for (row,col d)
                if (u == h) Vh[ib] = acc;        // lane keeps its row parity
            }
        }
        // 4-lane transpose over dd (lane bits 1..2): lane (h,dd) assembles the
        // full 4-channel segment of row rr = ob*8 + dd*2 + h.
        float f[4];
        f[dd]     = Vh[dd];
        f[dd ^ 1] = __shfl_xor(Vh[dd ^ 1], 2);
        f[dd ^ 2] = __shfl_xor(Vh[dd ^ 2], 4);
        f[dd ^ 3] = __shfl_xor(Vh[dd ^ 3], 6);
        int row = ct * T + ob * 8 + dd * 2 + h;
        *(float4*)(out + (size_t)row * D + d0) =
            make_float4(f[0], f[1], f[2], f[3]);   // 16 B/lane store
    }
}

extern "C" void kernel_launch(void* const* d_in, const int* in_sizes, int n_in,
                              void* d_out, int out_size, void* d_ws, size_t ws_size,
                              hipStream_t stream) {
    const float* x     = (const float*)d_in[0];
    const float* Delta = (const float*)d_in[1];
    const float* A_re  = (const float*)d_in[2];
    const float* A_im  = (const float*)d_in[3];
    const float* B_re  = (const float*)d_in[4];
    const float* B_im  = (const float*)d_in[5];
    const float* C_re  = (const float*)d_in[6];
    const float* C_im  = (const float*)d_in[7];
    const float* Dp    = (const float*)d_in[8];
    float* out = (float*)d_out;

    k_fused<<<NB, NT, 0, stream>>>(x, Delta, A_re, A_im, B_re, B_im,
                                   C_re, C_im, Dp, out);
}